// Round 1
// baseline (605.825 us; speedup 1.0000x reference)
//
#include <hip/hip_runtime.h>

// VectorQuantizer: B=16, T=4096, D=256, K=1024 (fp32 in, fp32 out).
// out[t] = codebook[argmin_k ||x_t - c_k||^2], argmin via c2[k] - 2*x.c.
// Round 1: correct fp32 vector-ALU tiled GEMM + fused argmin.

#define DDIM      256
#define KCODES    1024
#define NTOK      65536
#define TOK_TILE  64
#define CODE_CHUNK 64
#define D_CHUNK   32
#define LDS_STRIDE 68   // 68 floats = 272B rows: 16B-aligned, bank-quad spread

// ---------- kernel A: c2[k] = ||codebook[k]||^2 ----------
__global__ __launch_bounds__(256) void vq_c2_kernel(const float* __restrict__ cb,
                                                    float* __restrict__ c2) {
    const int k    = blockIdx.x * 4 + (threadIdx.x >> 6);   // 4 codes per block
    const int lane = threadIdx.x & 63;
    const float4 v = *(const float4*)(cb + (size_t)k * DDIM + 4 * lane);
    float s = v.x * v.x + v.y * v.y + v.z * v.z + v.w * v.w;
    #pragma unroll
    for (int off = 32; off > 0; off >>= 1) s += __shfl_down(s, off, 64);
    if (lane == 0) c2[k] = s;
}

// ---------- kernel B: fused distance-GEMM + argmin + gather ----------
__global__ __launch_bounds__(256) void vq_main_kernel(const float* __restrict__ xg,
                                                      const float* __restrict__ cb,
                                                      const float* __restrict__ c2,
                                                      float* __restrict__ out) {
    __shared__ __align__(16) float xs[D_CHUNK][LDS_STRIDE];  // [d][token]
    __shared__ __align__(16) float cs[D_CHUNK][LDS_STRIDE];  // [d][code]
    __shared__ float redv[TOK_TILE][16];
    __shared__ int   redi[TOK_TILE][16];
    __shared__ int   idx_s[TOK_TILE];

    const int t    = threadIdx.x;
    const int tm   = t & 15;          // token group: tokens 4*tm..4*tm+3
    const int tn   = t >> 4;          // code group:  codes  4*tn..4*tn+3 (chunk-local)
    const int tok0 = blockIdx.x * TOK_TILE;

    float bestv[4] = {3.4e38f, 3.4e38f, 3.4e38f, 3.4e38f};
    int   besti[4] = {0, 0, 0, 0};

    for (int kc = 0; kc < KCODES / CODE_CHUNK; ++kc) {
        float acc[4][4];
        #pragma unroll
        for (int i = 0; i < 4; ++i)
            #pragma unroll
            for (int j = 0; j < 4; ++j) acc[i][j] = 0.0f;

        for (int dc = 0; dc < DDIM / D_CHUNK; ++dc) {
            __syncthreads();  // protect LDS from previous iter's readers
            // stage X tile: 64 tok x 32 d (transpose to d-major)
            #pragma unroll
            for (int i = 0; i < 2; ++i) {
                const int idx = t + 256 * i;          // 0..511 float4 slots
                const int tok = idx >> 3;             // 0..63
                const int d4  = idx & 7;              // 0..7
                const float4 v = *(const float4*)(xg + (size_t)(tok0 + tok) * DDIM
                                                  + dc * D_CHUNK + 4 * d4);
                xs[4 * d4 + 0][tok] = v.x;
                xs[4 * d4 + 1][tok] = v.y;
                xs[4 * d4 + 2][tok] = v.z;
                xs[4 * d4 + 3][tok] = v.w;
            }
            // stage C tile: 64 codes x 32 d (transpose to d-major)
            #pragma unroll
            for (int i = 0; i < 2; ++i) {
                const int idx  = t + 256 * i;
                const int code = idx >> 3;            // 0..63
                const int d4   = idx & 7;
                const float4 v = *(const float4*)(cb + (size_t)(kc * CODE_CHUNK + code) * DDIM
                                                  + dc * D_CHUNK + 4 * d4);
                cs[4 * d4 + 0][code] = v.x;
                cs[4 * d4 + 1][code] = v.y;
                cs[4 * d4 + 2][code] = v.z;
                cs[4 * d4 + 3][code] = v.w;
            }
            __syncthreads();

            #pragma unroll
            for (int d = 0; d < D_CHUNK; ++d) {
                const float4 xv = *(const float4*)&xs[d][4 * tm];
                const float4 cv = *(const float4*)&cs[d][4 * tn];
                const float xa[4] = {xv.x, xv.y, xv.z, xv.w};
                const float ca[4] = {cv.x, cv.y, cv.z, cv.w};
                #pragma unroll
                for (int i = 0; i < 4; ++i)
                    #pragma unroll
                    for (int j = 0; j < 4; ++j)
                        acc[i][j] = fmaf(xa[i], ca[j], acc[i][j]);
            }
        }

        // fold this chunk into running best (codes ascend => strict < keeps
        // first occurrence, matching jnp.argmin tie-breaking)
        #pragma unroll
        for (int j = 0; j < 4; ++j) {
            const int code = kc * CODE_CHUNK + 4 * tn + j;
            const float cc = c2[code];
            #pragma unroll
            for (int i = 0; i < 4; ++i) {
                const float dist = fmaf(-2.0f, acc[i][j], cc);
                if (dist < bestv[i]) { bestv[i] = dist; besti[i] = code; }
            }
        }
    }

    // cross-thread (tn) reduction per token
    #pragma unroll
    for (int i = 0; i < 4; ++i) {
        redv[4 * tm + i][tn] = bestv[i];
        redi[4 * tm + i][tn] = besti[i];
    }
    __syncthreads();
    if (t < TOK_TILE) {
        float bv = redv[t][0];
        int   bi = redi[t][0];
        #pragma unroll
        for (int n = 1; n < 16; ++n) {
            const float v = redv[t][n];
            const int   i2 = redi[t][n];
            if (v < bv || (v == bv && i2 < bi)) { bv = v; bi = i2; }
        }
        idx_s[t] = bi;
    }
    __syncthreads();

    // gather epilogue: out[tok] = codebook[idx[tok]], fully coalesced
    #pragma unroll
    for (int j = 0; j < 16; ++j) {
        const int f   = j * 256 + t;   // float4 index within 64x256 tile
        const int tok = f >> 6;        // wave-uniform
        const int d4  = f & 63;
        const int code = idx_s[tok];
        const float4 v = *(const float4*)(cb + (size_t)code * DDIM + 4 * d4);
        *(float4*)(out + (size_t)(tok0 + tok) * DDIM + 4 * d4) = v;
    }
}

extern "C" void kernel_launch(void* const* d_in, const int* in_sizes, int n_in,
                              void* d_out, int out_size, void* d_ws, size_t ws_size,
                              hipStream_t stream) {
    const float* x  = (const float*)d_in[0];   // [B,T,D] fp32
    const float* cb = (const float*)d_in[1];   // [K,D]   fp32
    float* out = (float*)d_out;                // [B,T,D] fp32
    float* c2  = (float*)d_ws;                 // K floats scratch

    hipLaunchKernelGGL(vq_c2_kernel, dim3(KCODES / 4), dim3(256), 0, stream, cb, c2);
    hipLaunchKernelGGL(vq_main_kernel, dim3(NTOK / TOK_TILE), dim3(256), 0, stream,
                       x, cb, c2, out);
}

// Round 2
// 282.783 us; speedup vs baseline: 2.1424x; 2.1424x over previous
//
#include <hip/hip_runtime.h>
#include <float.h>

// VectorQuantizer: B=16,T=4096,D=256,K=1024 fp32.
// Round 2: f16 MFMA distance GEMM + margin-gated exact-fp32 rescue.
//   d2 = c2[k] - 2*x.c  (x^2 term argmin-invariant)
//   main kernel: codes=M (LDS-streamed), tokens=N (register-resident f16 frags)
//   rescue: tokens with approx top2-gap < MARGIN recomputed in exact fp32.

typedef _Float16 f16;
typedef f16 f16x8 __attribute__((ext_vector_type(8)));
typedef f16 f16x4 __attribute__((ext_vector_type(4)));
typedef float f32x4 __attribute__((ext_vector_type(4)));

#define DDIM    256
#define KCODES  1024
#define NTOK    65536
#define MARGIN  0.2f
#define ASTRIDE 72   // f16 units per LDS row (64 data + 8 pad = 144B, 16B-aligned)

// ---------------- prep: codebook fp32->f16, c2, zero counter ----------------
__global__ __launch_bounds__(256) void vq_prep(const float* __restrict__ cb,
                                               f16* __restrict__ ch,
                                               float* __restrict__ c2,
                                               unsigned* __restrict__ count) {
    const int k    = blockIdx.x * 4 + (threadIdx.x >> 6);
    const int lane = threadIdx.x & 63;
    const float4 v = *(const float4*)(cb + (size_t)k * DDIM + 4 * lane);
    f16x4 h; h[0] = (f16)v.x; h[1] = (f16)v.y; h[2] = (f16)v.z; h[3] = (f16)v.w;
    *(f16x4*)(ch + (size_t)k * DDIM + 4 * lane) = h;
    float s = v.x * v.x + v.y * v.y + v.z * v.z + v.w * v.w;
    #pragma unroll
    for (int off = 32; off > 0; off >>= 1) s += __shfl_down(s, off, 64);
    if (lane == 0) c2[k] = s;
    if (blockIdx.x == 0 && threadIdx.x == 0) *count = 0u;
}

// ---------------- main: MFMA distances + fused argmin + gather ----------------
__global__ __launch_bounds__(256, 2) void vq_main(const float* __restrict__ xg,
                                                  const f16* __restrict__ ch,
                                                  const float* __restrict__ c2,
                                                  const float* __restrict__ cb,
                                                  float* __restrict__ out,
                                                  unsigned* __restrict__ count,
                                                  unsigned* __restrict__ list) {
    __shared__ f16 As[128 * ASTRIDE];          // codes chunk: 128 x 64 (BK)
    __shared__ float wmv[2][128];              // per code-half best val
    __shared__ int   wmi[2][128];
    __shared__ float wms[2][128];              // per code-half second val
    __shared__ float runv[128], runs[128];
    __shared__ int   runi[128];
    __shared__ int   idx_s[128];

    const int t    = threadIdx.x;
    const int wave = t >> 6, lane = t & 63;
    const int wm   = wave >> 1;                // code-half (M)
    const int tn   = wave & 1;                 // token-half (N)
    const int q    = lane >> 4;                // operand quad
    const int m16  = lane & 15;
    const int tok0 = blockIdx.x * 128;

    // ---- load token B-fragments, fp32 -> f16 in registers (once) ----
    // B[n = lane&15][k = q*8 + j], k-global = ks*32 + q*8 + j
    f16x8 bfrag[4][8];
    #pragma unroll
    for (int ti = 0; ti < 4; ++ti) {
        const size_t row = (size_t)(tok0 + tn * 64 + ti * 16 + m16) * DDIM;
        #pragma unroll
        for (int ks = 0; ks < 8; ++ks) {
            const float* p = xg + row + ks * 32 + q * 8;
            const float4 u0 = *(const float4*)(p);
            const float4 u1 = *(const float4*)(p + 4);
            f16x8 b;
            b[0] = (f16)u0.x; b[1] = (f16)u0.y; b[2] = (f16)u0.z; b[3] = (f16)u0.w;
            b[4] = (f16)u1.x; b[5] = (f16)u1.y; b[6] = (f16)u1.z; b[7] = (f16)u1.w;
            bfrag[ti][ks] = b;
        }
    }

    if (t < 128) { runv[t] = FLT_MAX; runs[t] = FLT_MAX; runi[t] = 0; }

    for (int nc = 0; nc < 8; ++nc) {           // 8 chunks of 128 codes
        f32x4 acc[4][4];                       // [ci][ti]
        #pragma unroll
        for (int ci = 0; ci < 4; ++ci)
            #pragma unroll
            for (int ti = 0; ti < 4; ++ti) acc[ci][ti] = (f32x4)0.0f;

        #pragma unroll
        for (int st = 0; st < 4; ++st) {       // BK=64 stages over K=256
            __syncthreads();
            // stage codes: 128 rows x 64 f16, b128 granules, padded rows
            #pragma unroll
            for (int i = 0; i < 4; ++i) {
                const int g   = t + 256 * i;   // 1024 granules of 8 f16
                const int row = g >> 3, c16 = g & 7;
                const f16x8 v = *(const f16x8*)(ch + (size_t)(nc * 128 + row) * DDIM
                                                + st * 64 + c16 * 8);
                *(f16x8*)(As + row * ASTRIDE + c16 * 8) = v;
            }
            __syncthreads();
            #pragma unroll
            for (int kk = 0; kk < 2; ++kk) {
                f16x8 af[4];
                #pragma unroll
                for (int ci = 0; ci < 4; ++ci)
                    af[ci] = *(const f16x8*)(As + (wm * 64 + ci * 16 + m16) * ASTRIDE
                                             + kk * 32 + q * 8);
                const int ksg = st * 2 + kk;
                #pragma unroll
                for (int ci = 0; ci < 4; ++ci)
                    #pragma unroll
                    for (int ti = 0; ti < 4; ++ti)
                        acc[ci][ti] = __builtin_amdgcn_mfma_f32_16x16x32_f16(
                            af[ci], bfrag[ti][ksg], acc[ci][ti], 0, 0, 0);
            }
        }

        // ---- chunk epilogue: per-token top-2 over 128 codes ----
        const int kbase = nc * 128 + wm * 64;
        float cc[4][4];                        // c2 per [ci][r]
        #pragma unroll
        for (int ci = 0; ci < 4; ++ci)
            #pragma unroll
            for (int r = 0; r < 4; ++r)
                cc[ci][r] = c2[kbase + ci * 16 + q * 4 + r];

        #pragma unroll
        for (int ti = 0; ti < 4; ++ti) {
            float b1 = FLT_MAX, b2 = FLT_MAX; int i1 = 0;
            #pragma unroll
            for (int ci = 0; ci < 4; ++ci) {   // ascending code order within lane
                #pragma unroll
                for (int r = 0; r < 4; ++r) {
                    const float d = fmaf(-2.0f, acc[ci][ti][r], cc[ci][r]);
                    const int   c = kbase + ci * 16 + q * 4 + r;
                    const bool lt = d < b1;
                    b2 = fminf(b2, lt ? b1 : d);
                    i1 = lt ? c : i1;
                    b1 = lt ? d : b1;
                }
            }
            // merge across the 4 quads (lanes l^16, l^32 share token)
            #pragma unroll
            for (int s = 0; s < 2; ++s) {
                const int off = 16 << s;
                const float ob1 = __shfl_xor(b1, off, 64);
                const float ob2 = __shfl_xor(b2, off, 64);
                const int   oi1 = __shfl_xor(i1, off, 64);
                const bool better = (ob1 < b1) || (ob1 == b1 && oi1 < i1);
                b2 = fminf(fminf(b2, ob2), fmaxf(b1, ob1));
                b1 = better ? ob1 : b1;
                i1 = better ? oi1 : i1;
            }
            if (lane < 16) {
                const int tl = tn * 64 + ti * 16 + m16;
                wmv[wm][tl] = b1; wmi[wm][tl] = i1; wms[wm][tl] = b2;
            }
        }
        __syncthreads();
        if (t < 128) {                          // merge code-halves, fold into running
            const float a1 = wmv[0][t], a2 = wms[0][t];
            const int   ai = wmi[0][t];
            const float b1_ = wmv[1][t], b2_ = wms[1][t];
            const int   bi_ = wmi[1][t];
            const bool bb = (b1_ < a1) || (b1_ == a1 && bi_ < ai);
            const float c1 = bb ? b1_ : a1;
            const int   ci_ = bb ? bi_ : ai;
            const float cs = fminf(fminf(a2, b2_), fmaxf(a1, b1_));
            const float r1 = runv[t];
            runs[t] = fminf(fminf(runs[t], cs), fmaxf(r1, c1));
            if (c1 < r1) { runv[t] = c1; runi[t] = ci_; }  // tie -> earlier chunk wins
        }
        // next chunk's first stage __syncthreads orders the wmv rewrite
    }

    __syncthreads();
    if (t < 128) {
        idx_s[t] = runi[t];
        if (runs[t] - runv[t] < MARGIN) {
            const unsigned p = atomicAdd(count, 1u);
            list[p] = tok0 + t;
        }
    }
    __syncthreads();

    // gather epilogue: out[tok] = cb[argmin], coalesced float4
    #pragma unroll
    for (int i = 0; i < 32; ++i) {
        const int f   = i * 256 + t;           // 8192 float4 = 128 tok x 64
        const int tok = f >> 6, d4 = f & 63;
        const int code = idx_s[tok];
        const float4 v = *(const float4*)(cb + (size_t)code * DDIM + 4 * d4);
        *(float4*)(out + (size_t)(tok0 + tok) * DDIM + 4 * d4) = v;
    }
}

// ---------------- rescue: exact fp32 argmin for margin-flagged tokens ----------------
__global__ __launch_bounds__(256) void vq_rescue(const float* __restrict__ xg,
                                                 const float* __restrict__ cb,
                                                 const float* __restrict__ c2,
                                                 const unsigned* __restrict__ count,
                                                 const unsigned* __restrict__ list,
                                                 float* __restrict__ out) {
    __shared__ float xls[8][DDIM];
    __shared__ float rv[4];
    __shared__ int   ri[4];
    __shared__ int   bidx[8];

    const int t = threadIdx.x;
    const int wave = t >> 6, lane = t & 63;
    const unsigned n = *count;

    for (unsigned base = blockIdx.x * 8; base < n; base += gridDim.x * 8) {
        const int nb = (int)min(8u, n - base);
        __syncthreads();
        #pragma unroll
        for (int i = 0; i < 2; ++i) {
            const int f = t + 256 * i;          // 512 float4 slots
            const int row = f >> 6, d4 = f & 63;
            if (row < nb)
                *(float4*)&xls[row][4 * d4] =
                    *(const float4*)(xg + (size_t)list[base + row] * DDIM + 4 * d4);
        }
        __syncthreads();

        float acc[4][8];
        #pragma unroll
        for (int j = 0; j < 4; ++j)
            #pragma unroll
            for (int tk = 0; tk < 8; ++tk) acc[j][tk] = 0.0f;

        for (int d4 = 0; d4 < 64; ++d4) {
            float4 xv[8];
            #pragma unroll
            for (int tk = 0; tk < 8; ++tk) xv[tk] = *(const float4*)&xls[tk][4 * d4];
            #pragma unroll
            for (int j = 0; j < 4; ++j) {
                const float4 cv = *(const float4*)(cb + (size_t)(4 * t + j) * DDIM + 4 * d4);
                #pragma unroll
                for (int tk = 0; tk < 8; ++tk) {
                    // sequential .x->.w accumulation: matches round-1-verified order
                    float a = acc[j][tk];
                    a = fmaf(cv.x, xv[tk].x, a);
                    a = fmaf(cv.y, xv[tk].y, a);
                    a = fmaf(cv.z, xv[tk].z, a);
                    a = fmaf(cv.w, xv[tk].w, a);
                    acc[j][tk] = a;
                }
            }
        }

        for (int tk = 0; tk < nb; ++tk) {
            float b1 = FLT_MAX; int i1 = 0;
            #pragma unroll
            for (int j = 0; j < 4; ++j) {       // codes 4t..4t+3 ascending
                const float d = fmaf(-2.0f, acc[j][tk], c2[4 * t + j]);
                if (d < b1) { b1 = d; i1 = 4 * t + j; }
            }
            #pragma unroll
            for (int off = 32; off > 0; off >>= 1) {
                const float ov = __shfl_xor(b1, off, 64);
                const int   oi = __shfl_xor(i1, off, 64);
                if (ov < b1 || (ov == b1 && oi < i1)) { b1 = ov; i1 = oi; }
            }
            if (lane == 0) { rv[wave] = b1; ri[wave] = i1; }
            __syncthreads();
            if (t == 0) {
                float bv = rv[0]; int bi = ri[0];
                #pragma unroll
                for (int w = 1; w < 4; ++w)
                    if (rv[w] < bv || (rv[w] == bv && ri[w] < bi)) { bv = rv[w]; bi = ri[w]; }
                bidx[tk] = bi;
            }
            __syncthreads();
        }

        #pragma unroll
        for (int i = 0; i < 2; ++i) {
            const int f = t + 256 * i;
            const int row = f >> 6, d4 = f & 63;
            if (row < nb) {
                const int code = bidx[row];
                const float4 v = *(const float4*)(cb + (size_t)code * DDIM + 4 * d4);
                *(float4*)(out + (size_t)list[base + row] * DDIM + 4 * d4) = v;
            }
        }
    }
}

extern "C" void kernel_launch(void* const* d_in, const int* in_sizes, int n_in,
                              void* d_out, int out_size, void* d_ws, size_t ws_size,
                              hipStream_t stream) {
    const float* x  = (const float*)d_in[0];   // [B,T,D] fp32
    const float* cb = (const float*)d_in[1];   // [K,D]   fp32
    float* out = (float*)d_out;

    char* ws = (char*)d_ws;
    f16*      ch    = (f16*)ws;                              // 524288 B
    float*    c2    = (float*)(ws + 524288);                 // 4096 B
    unsigned* count = (unsigned*)(ws + 528448);              // 4 B (padded)
    unsigned* list  = (unsigned*)(ws + 528512);              // 262144 B

    hipLaunchKernelGGL(vq_prep,   dim3(KCODES / 4), dim3(256), 0, stream, cb, ch, c2, count);
    hipLaunchKernelGGL(vq_main,   dim3(NTOK / 128), dim3(256), 0, stream,
                       x, ch, c2, cb, out, count, list);
    hipLaunchKernelGGL(vq_rescue, dim3(128),        dim3(256), 0, stream,
                       x, cb, c2, count, list, out);
}